// Round 2
// baseline (151.417 us; speedup 1.0000x reference)
//
#include <hip/hip_runtime.h>
#include <hip/hip_bf16.h>

#define BATCH 8
#define MAXPOS 2048
#define SEQ 2046
#define NH 12
#define HD 64
#define NCSLOT 254      // ci = c/16 in [-127,126], cslot = ci+127
#define TSTEPS 64       // K-chunks of 32 covering t=0..2047 (zero-padded past 2045)
#define PLANE (NH * HD) // 768

typedef __attribute__((ext_vector_type(4))) float floatx4;
typedef __attribute__((ext_vector_type(8))) short shortx8;

// ws layout: [Atile: 12*254*512 bf16 = 3,121,152 B][Vbf: 8*12*256*512 bf16 = 25,165,824 B]
#define ATILE_BYTES (NH * NCSLOT * 512 * 2)

#define GLOAD_LDS16(src, dst)                                                  \
    __builtin_amdgcn_global_load_lds(                                          \
        (const __attribute__((address_space(1))) void*)(src),                  \
        (__attribute__((address_space(3))) void*)(dst), 16, 0, 0)

// Block ranges inside prep_all
#define NB_V   (TSTEPS * NH * BATCH)   // 6144
#define NB_ZPB NH                      // 12
#define NB_A   (NCSLOT * NH)           // 3048

// ---------------------------------------------------------------------------
// prep_all: single prologue kernel (UNCHANGED this round).
// ---------------------------------------------------------------------------
__global__ __launch_bounds__(256)
void prep_all(const float* __restrict__ v, const float* __restrict__ w,
              const float* __restrict__ off, ushort* __restrict__ atile,
              ushort* __restrict__ vbf, float* __restrict__ out) {
    const int bi  = blockIdx.x;
    const int tid = threadIdx.x;

    if (bi < NB_V) {
        // ---- prep_V: block = (tc,h,b); col-swizzle (key=q*16) kills 4-way conflict
        __shared__ float Ls[32][64];
        const int tc = bi & 63;
        int rem = bi >> 6;
        const int h = rem % NH;
        const int b = rem / NH;
#pragma unroll
        for (int i = 0; i < 2; ++i) {
            int idx = tid + 256 * i;
            int row = idx >> 4;
            int c4  = (idx & 15) * 4;
            int key = (row >> 3) * 16;
            int t   = tc * 32 + row;
            float4 val = make_float4(0.f, 0.f, 0.f, 0.f);
            if (t < SEQ) val = *(const float4*)(v + ((size_t)(b * MAXPOS + 1 + t) * NH + h) * HD + c4);
            *(float4*)&Ls[row][c4 ^ key] = val;
        }
        __syncthreads();
        const int wv   = tid >> 6;
        const int lane = tid & 63;
        const int q    = lane >> 4;
        const int dcol = lane & 15;
        ushort pk[8];
#pragma unroll
        for (int j = 0; j < 8; ++j) {
            __hip_bfloat16 bv = __float2bfloat16(Ls[q * 8 + j][(wv * 16 + dcol) ^ (q * 16)]);
            pk[j] = *(ushort*)&bv;
        }
        *(uint4*)(vbf + ((size_t)((b * NH + h) * TSTEPS + tc) * 4 + wv) * 512 + lane * 8) = *(uint4*)pk;
    } else if (bi < NB_V + NB_ZPB) {
        // ---- zpb scan
        __shared__ float Es[SEQ];
        __shared__ float Ss[SEQ];
        __shared__ float wsum[4];
        const int h    = bi - NB_V;
        const int wid  = tid >> 6;
        const int lane = tid & 63;
        const float offh = off[h];
        const float* wh  = w + h * SEQ;
        for (int i = tid; i < SEQ; i += 256) Es[i] = __expf(wh[i] - offh);
        __syncthreads();
        const int base = tid * 8;
        float loc[8];
        float s = 0.f;
#pragma unroll
        for (int j = 0; j < 8; ++j) {
            float e = (base + j < SEQ) ? Es[base + j] : 0.f;
            s += e; loc[j] = s;
        }
        float sc = s;
#pragma unroll
        for (int d = 1; d < 64; d <<= 1) {
            float t = __shfl_up(sc, d);
            if (lane >= d) sc += t;
        }
        if (lane == 63) wsum[wid] = sc;
        __syncthreads();
        float woff = 0.f;
        for (int k = 0; k < wid; ++k) woff += wsum[k];
        float prefix = woff + sc - s;
#pragma unroll
        for (int j = 0; j < 8; ++j)
            if (base + j < SEQ) Ss[base + j] = prefix + loc[j];
        __syncthreads();
        const float E0 = Es[0];
        const size_t zb = (size_t)BATCH * MAXPOS * PLANE;
        for (int i = tid; i < SEQ; i += 256)
            out[zb + (size_t)(i + 1) * NH + h] = Ss[i] + Ss[SEQ - 1 - i] - E0;
    } else if (bi < NB_V + NB_ZPB + NB_A) {
        // ---- prep_A: tile (h,cslot) elem[lane][j]=exp(w[h,|16ci+(lane>>4)*8-(lane&15)+j|]-off)
        const int idx   = bi - NB_V - NB_ZPB;
        const int cslot = idx % NCSLOT;
        const int h     = idx / NCSLOT;
        const float offh = off[h];
        const float* wh  = w + h * SEQ;
        const int ci   = cslot - 127;
        const int lane = tid >> 2;
        const int jp   = (tid & 3) * 2;
        const int q    = lane >> 4;
        const int m    = lane & 15;
        const int d0   = 16 * ci + q * 8 - m + jp;
        ushort pk[2];
#pragma unroll
        for (int e = 0; e < 2; ++e) {
            int k = d0 + e; k = (k < 0) ? -k : k;
            float val = (k < SEQ) ? __expf(wh[k] - offh) : 0.f;
            __hip_bfloat16 bv = __float2bfloat16(val);
            pk[e] = *(ushort*)&bv;
        }
        *(ushort2*)(atile + ((size_t)(h * NCSLOT + cslot) * 512 + lane * 8 + jp)) = *(ushort2*)pk;
    } else {
        // ---- zero boundary positions (p=0, p=2047) of both outputs
        const int i = (bi - NB_V - NB_ZPB - NB_A) * 256 + tid;
        if (i < 2 * BATCH * PLANE) {
            int side = i / (BATCH * PLANE);
            int r    = i % (BATCH * PLANE);
            int b    = r / PLANE;
            int j    = r % PLANE;
            int p    = side ? (MAXPOS - 1) : 0;
            out[((size_t)b * MAXPOS + p) * PLANE + j] = 0.f;
        }
        if (i < 2 * NH) {
            size_t zb = (size_t)BATCH * MAXPOS * PLANE;
            int p = (i < NH) ? 0 : (MAXPOS - 1);
            out[zb + (size_t)p * NH + (i % NH)] = 0.f;
        }
    }
}

// ---------------------------------------------------------------------------
// gemm_pbv (R2): BARRIER-FREE wave-private pipeline.
//   Block = 256 rows(n) x 64 d x 1 batch; wave wv owns rows [wv*64, wv*64+64)
//   -> the 4 A-frags (fs = wv*4+k) a wave consumes are staged BY that wave
//   into its PRIVATE LDS ring (ring-3, 4 KB/step, 12 KB/wave, 48 KB/block).
//   No fragment is shared across waves => ZERO s_barrier in the kernel.
//   Per step per wave: 4 global_load_lds (A, 1 KB each) + 4 b128 loads (B)
//   = 8 VMEM ops; "s_waitcnt vmcnt(8)" between steps keeps one full step's
//   8 ops in flight at all times (2-step issue-to-consume distance).
//   WAR safety (ring-3): slot (tc+2)%3 == (tc-1)%3 was last ds_read at step
//   tc-1; those reads are lgkm-drained before step tc-1's MFMAs, which
//   precede (in wave program order) step tc's stage issue. Wave-private =>
//   no cross-wave hazard. s_setprio(1/0) wraps each 16-MFMA cluster (T5,
//   now in the independent-wave regime where it measurably pays).
// ---------------------------------------------------------------------------

#define FENCE  asm volatile("" ::: "memory")
#define WAITV8 asm volatile("s_waitcnt vmcnt(8)" ::: "memory")
#define WAITV0 asm volatile("s_waitcnt vmcnt(0)" ::: "memory")

// One K-step tc: read A(tc) frags from private ring slot RING, stage A(tc+2)
// into slot NXT (4 gload_lds), 16 MFMA on b[BS], prefetch B(tc+2) into b[BS].
// E = step index within the current cursor window (A src = aQ + (2E-k)*512,
// B src = bQ + E*2048). STG=0 for the two peeled tail steps.
#define GEMM_STEP(RING, NXT, BS, STG, E)                                       \
  do {                                                                         \
    shortx8 aa[4];                                                             \
    _Pragma("unroll")                                                          \
    for (int s = 0; s < 4; ++s)                                                \
        aa[s] = *(const shortx8*)(aR + (RING) * 2048 + s * 512);               \
    if (STG) {                                                                 \
        GLOAD_LDS16(aQ + (2 * (E) - 0) * 512, aW + (NXT) * 2048 + 0 * 512);    \
        GLOAD_LDS16(aQ + (2 * (E) - 1) * 512, aW + (NXT) * 2048 + 1 * 512);    \
        GLOAD_LDS16(aQ + (2 * (E) - 2) * 512, aW + (NXT) * 2048 + 2 * 512);    \
        GLOAD_LDS16(aQ + (2 * (E) - 3) * 512, aW + (NXT) * 2048 + 3 * 512);    \
    }                                                                          \
    __builtin_amdgcn_s_setprio(1);                                             \
    _Pragma("unroll")                                                          \
    for (int s = 0; s < 4; ++s)                                                \
        _Pragma("unroll")                                                      \
        for (int dt = 0; dt < 4; ++dt)                                         \
            acc[s][dt] = __builtin_amdgcn_mfma_f32_16x16x32_bf16(              \
                aa[s], b[BS][dt], acc[s][dt], 0, 0, 0);                        \
    __builtin_amdgcn_s_setprio(0);                                             \
    if (STG) {                                                                 \
        _Pragma("unroll")                                                      \
        for (int dt = 0; dt < 4; ++dt)                                         \
            b[BS][dt] = *(const shortx8*)(bQ + (E) * 2048 + dt * 512);         \
    }                                                                          \
  } while (0)

__global__ __launch_bounds__(256, 3)
void gemm_pbv(const ushort* __restrict__ atile, const ushort* __restrict__ vbf,
              float* __restrict__ out) {
    // [wave][ring slot][frag][512 bf16] = 48 KB
    __shared__ short As[4][3][4][512];

    // swizzle: cluster the 8 nt-blocks sharing one (h,bb) B-stream per XCD
    const int bid     = blockIdx.x;            // 0..767
    const int logical = (bid & 7) * 96 + (bid >> 3);
    const int g       = logical >> 3;          // (h,bb) group 0..95
    const int nt      = logical & 7;           // 256-row tile 0..7
    const int h       = g >> 3;                // 0..11
    const int bb      = g & 7;                 // 0..7
    const int tid     = threadIdx.x;
    const int wv      = tid >> 6;              // wave owns rows nt*256+wv*64..+63
    const int lane    = tid & 63;

    floatx4 acc[4][4];
#pragma unroll
    for (int s = 0; s < 4; ++s)
#pragma unroll
        for (int dt = 0; dt < 4; ++dt) acc[s][dt] = (floatx4){0.f, 0.f, 0.f, 0.f};

    // A frag (tc, k): cslot = 2*tc - (nt*16 + wv*4 + k) + 127  (in [0,253])
    const ushort* aS = atile + ((size_t)h * NCSLOT + (127 - nt * 16 - wv * 4)) * 512 + lane * 8;
    const ushort* bP = vbf + (size_t)(bb * NH + h) * (TSTEPS * 4 * 512) + lane * 8;
    short*       aW = &As[wv][0][0][0];            // wave-uniform stage base
    const short* aR = &As[wv][0][0][0] + lane * 8; // frag read base

    shortx8 b[2][4];

    // ---- prologue: S(0) region [8 VMEM], fence, S(1) region [8 VMEM]
    GLOAD_LDS16(aS - 0 * 512, aW + 0 * 512);
    GLOAD_LDS16(aS - 1 * 512, aW + 1 * 512);
    GLOAD_LDS16(aS - 2 * 512, aW + 2 * 512);
    GLOAD_LDS16(aS - 3 * 512, aW + 3 * 512);
#pragma unroll
    for (int dt = 0; dt < 4; ++dt) b[0][dt] = *(const shortx8*)(bP + dt * 512);
    FENCE;  // region split: newest-8 at the wait below = exactly S(1)
    GLOAD_LDS16(aS + (2 - 0) * 512, aW + 2048 + 0 * 512);
    GLOAD_LDS16(aS + (2 - 1) * 512, aW + 2048 + 1 * 512);
    GLOAD_LDS16(aS + (2 - 2) * 512, aW + 2048 + 2 * 512);
    GLOAD_LDS16(aS + (2 - 3) * 512, aW + 2048 + 3 * 512);
#pragma unroll
    for (int dt = 0; dt < 4; ++dt) b[1][dt] = *(const shortx8*)(bP + 2048 + dt * 512);
    WAITV8;   // S(0) landed (A(0) in this wave's LDS, B(0) in regs)

    // cursors for the step staged 2 ahead (tc+2); at loop top (tc=6u): base tc+2=6u+2
    const ushort* aQ = aS + 4 * 512;      // = A src base for (tc+2=2, E=0)
    const ushort* bQ = bP + 2 * 2048;

    // ---- main loop: tc = 0..59 (period 6 = lcm(ring 3, bbuf 2)), no barriers
    for (int u = 0; u < 10; ++u) {
        GEMM_STEP(0, 2, 0, 1, 0); WAITV8;
        GEMM_STEP(1, 0, 1, 1, 1); WAITV8;
        GEMM_STEP(2, 1, 0, 1, 2); WAITV8;
        GEMM_STEP(0, 2, 1, 1, 3); WAITV8;
        GEMM_STEP(1, 0, 0, 1, 4); WAITV8;
        GEMM_STEP(2, 1, 1, 1, 5); WAITV8;
        aQ += 12 * 512;
        bQ += 6 * 2048;
    }
    // ---- peeled tail: tc = 60..63 (aQ/bQ base at tc+2 = 62, E=0)
    GEMM_STEP(0, 2, 0, 1, 0); WAITV8;   // tc=60: stages S(62)->ring2
    GEMM_STEP(1, 0, 1, 1, 1); WAITV8;   // tc=61: stages S(63)->ring0
    GEMM_STEP(2, 0, 0, 0, 0); WAITV0;   // tc=62: no stage; drain S(63)
    GEMM_STEP(0, 0, 1, 0, 0);           // tc=63: final compute

    // epilogue: D row=(lane>>4)*4+r (n-local), col=lane&15 (d-local)
    const int q    = lane >> 4;
    const int dcol = lane & 15;
    const int nB   = nt * 256 + wv * 64;
#pragma unroll
    for (int s = 0; s < 4; ++s) {
        int nsb = nB + s * 16 + q * 4;
#pragma unroll
        for (int r = 0; r < 4; ++r) {
            int n = nsb + r;
            if (n < SEQ) {
                float* ob = out + ((size_t)(bb * MAXPOS + 1 + n) * NH + h) * HD + dcol;
#pragma unroll
                for (int dt = 0; dt < 4; ++dt) ob[dt * 16] = acc[s][dt][r];
            }
        }
    }
}

extern "C" void kernel_launch(void* const* d_in, const int* in_sizes, int n_in,
                              void* d_out, int out_size, void* d_ws, size_t ws_size,
                              hipStream_t stream) {
    const float* v   = (const float*)d_in[0];  // (8, 2048, 12, 64)
    const float* off = (const float*)d_in[1];  // (1, 12)
    const float* w   = (const float*)d_in[2];  // (1, 12, 2046)
    float* out = (float*)d_out;

    ushort* atile = (ushort*)d_ws;
    ushort* vbf   = (ushort*)((char*)d_ws + ATILE_BYTES);

    prep_all<<<NB_V + NB_ZPB + NB_A + 48, 256, 0, stream>>>(v, w, off, atile, vbf, out);
    gemm_pbv<<<768, 256, 0, stream>>>(atile, vbf, out);
}

// Round 4
// 145.077 us; speedup vs baseline: 1.0437x; 1.0437x over previous
//
#include <hip/hip_runtime.h>
#include <hip/hip_bf16.h>

#define BATCH 8
#define MAXPOS 2048
#define SEQ 2046
#define NH 12
#define HD 64
#define NCSLOT 254      // ci = c/16 in [-127,126], cslot = ci+127
#define TSTEPS 64       // K-chunks of 32 covering t=0..2047 (zero-padded past 2045)
#define PLANE (NH * HD) // 768

typedef __attribute__((ext_vector_type(4))) float floatx4;
typedef __attribute__((ext_vector_type(8))) short shortx8;

// ws layout: [Atile: 12*254*512 bf16 = 3,121,152 B][Vbf: 8*12*256*512 bf16 = 25,165,824 B]
#define ATILE_BYTES (NH * NCSLOT * 512 * 2)

#define GLOAD_LDS16(src, dst)                                                  \
    __builtin_amdgcn_global_load_lds(                                          \
        (const __attribute__((address_space(1))) void*)(src),                  \
        (__attribute__((address_space(3))) void*)(dst), 16, 0, 0)

// Block ranges inside prep_all
#define NB_V   (TSTEPS * NH * BATCH)   // 6144
#define NB_ZPB NH                      // 12
#define NB_A   (NCSLOT * NH)           // 3048

// ---------------------------------------------------------------------------
// prep_all: single prologue kernel (UNCHANGED).
// ---------------------------------------------------------------------------
__global__ __launch_bounds__(256)
void prep_all(const float* __restrict__ v, const float* __restrict__ w,
              const float* __restrict__ off, ushort* __restrict__ atile,
              ushort* __restrict__ vbf, float* __restrict__ out) {
    const int bi  = blockIdx.x;
    const int tid = threadIdx.x;

    if (bi < NB_V) {
        // ---- prep_V: block = (tc,h,b); col-swizzle (key=q*16) kills 4-way conflict
        __shared__ float Ls[32][64];
        const int tc = bi & 63;
        int rem = bi >> 6;
        const int h = rem % NH;
        const int b = rem / NH;
#pragma unroll
        for (int i = 0; i < 2; ++i) {
            int idx = tid + 256 * i;
            int row = idx >> 4;
            int c4  = (idx & 15) * 4;
            int key = (row >> 3) * 16;
            int t   = tc * 32 + row;
            float4 val = make_float4(0.f, 0.f, 0.f, 0.f);
            if (t < SEQ) val = *(const float4*)(v + ((size_t)(b * MAXPOS + 1 + t) * NH + h) * HD + c4);
            *(float4*)&Ls[row][c4 ^ key] = val;
        }
        __syncthreads();
        const int wv   = tid >> 6;
        const int lane = tid & 63;
        const int q    = lane >> 4;
        const int dcol = lane & 15;
        ushort pk[8];
#pragma unroll
        for (int j = 0; j < 8; ++j) {
            __hip_bfloat16 bv = __float2bfloat16(Ls[q * 8 + j][(wv * 16 + dcol) ^ (q * 16)]);
            pk[j] = *(ushort*)&bv;
        }
        *(uint4*)(vbf + ((size_t)((b * NH + h) * TSTEPS + tc) * 4 + wv) * 512 + lane * 8) = *(uint4*)pk;
    } else if (bi < NB_V + NB_ZPB) {
        // ---- zpb scan
        __shared__ float Es[SEQ];
        __shared__ float Ss[SEQ];
        __shared__ float wsum[4];
        const int h    = bi - NB_V;
        const int wid  = tid >> 6;
        const int lane = tid & 63;
        const float offh = off[h];
        const float* wh  = w + h * SEQ;
        for (int i = tid; i < SEQ; i += 256) Es[i] = __expf(wh[i] - offh);
        __syncthreads();
        const int base = tid * 8;
        float loc[8];
        float s = 0.f;
#pragma unroll
        for (int j = 0; j < 8; ++j) {
            float e = (base + j < SEQ) ? Es[base + j] : 0.f;
            s += e; loc[j] = s;
        }
        float sc = s;
#pragma unroll
        for (int d = 1; d < 64; d <<= 1) {
            float t = __shfl_up(sc, d);
            if (lane >= d) sc += t;
        }
        if (lane == 63) wsum[wid] = sc;
        __syncthreads();
        float woff = 0.f;
        for (int k = 0; k < wid; ++k) woff += wsum[k];
        float prefix = woff + sc - s;
#pragma unroll
        for (int j = 0; j < 8; ++j)
            if (base + j < SEQ) Ss[base + j] = prefix + loc[j];
        __syncthreads();
        const float E0 = Es[0];
        const size_t zb = (size_t)BATCH * MAXPOS * PLANE;
        for (int i = tid; i < SEQ; i += 256)
            out[zb + (size_t)(i + 1) * NH + h] = Ss[i] + Ss[SEQ - 1 - i] - E0;
    } else if (bi < NB_V + NB_ZPB + NB_A) {
        // ---- prep_A: tile (h,cslot) elem[lane][j]=exp(w[h,|16ci+(lane>>4)*8-(lane&15)+j|]-off)
        const int idx   = bi - NB_V - NB_ZPB;
        const int cslot = idx % NCSLOT;
        const int h     = idx / NCSLOT;
        const float offh = off[h];
        const float* wh  = w + h * SEQ;
        const int ci   = cslot - 127;
        const int lane = tid >> 2;
        const int jp   = (tid & 3) * 2;
        const int q    = lane >> 4;
        const int m    = lane & 15;
        const int d0   = 16 * ci + q * 8 - m + jp;
        ushort pk[2];
#pragma unroll
        for (int e = 0; e < 2; ++e) {
            int k = d0 + e; k = (k < 0) ? -k : k;
            float val = (k < SEQ) ? __expf(wh[k] - offh) : 0.f;
            __hip_bfloat16 bv = __float2bfloat16(val);
            pk[e] = *(ushort*)&bv;
        }
        *(ushort2*)(atile + ((size_t)(h * NCSLOT + cslot) * 512 + lane * 8 + jp)) = *(ushort2*)pk;
    } else {
        // ---- zero boundary positions (p=0, p=2047) of both outputs
        const int i = (bi - NB_V - NB_ZPB - NB_A) * 256 + tid;
        if (i < 2 * BATCH * PLANE) {
            int side = i / (BATCH * PLANE);
            int r    = i % (BATCH * PLANE);
            int b    = r / PLANE;
            int j    = r % PLANE;
            int p    = side ? (MAXPOS - 1) : 0;
            out[((size_t)b * MAXPOS + p) * PLANE + j] = 0.f;
        }
        if (i < 2 * NH) {
            size_t zb = (size_t)BATCH * MAXPOS * PLANE;
            int p = (i < NH) ? 0 : (MAXPOS - 1);
            out[zb + (size_t)p * NH + (i % NH)] = 0.f;
        }
    }
}

// ---------------------------------------------------------------------------
// gemm_pbv (R4): R1 geometry (wave=64n x 64d x 1b, shared A staging, 4-wave
// blocks, 768 blocks = 3/CU) with the pipeline deepened to DISTANCE-3:
//   - step tc stages A(tc+3) (2 global_load_lds) into RING-6 LDS slot
//     (tc+3)%6 and prefetches B(tc+3) into triple reg buffer b[tc%3].
//   - one fused "s_waitcnt vmcnt(12); s_barrier" per step keeps 2 full steps
//     (12 VMEM ops) in flight; drains loads issued 2 steps earlier (~2x R1's
//     latency tolerance). vmcnt reaches 0 only in the 3-step drain tail.
//   - WAR safety (the R3 fix): ring-6 means stage slot (tc+3)%6 was last
//     ds_read at step tc-3 -> THREE barriers separate last read from the
//     overwrite issue, immune to compiler MFMA-sinking across asm barriers
//     (rule #18). LDS = 48 KB, 3 blocks/CU = 144 KB <= 160 KB.
//   - "memory" clobbers pin per-region VMEM composition (6 ops/step), so
//     vmcnt(12) always means "everything up to S(tc+1) has landed".
//   - s_setprio(1/0) around each 16-MFMA cluster (kept from R1).
// Period = lcm(ring 6, bbuf 3) = 6 -> compact unroll; all indices static.
// ---------------------------------------------------------------------------

#define FENCE     asm volatile("" ::: "memory")
#define WAITBAR12 asm volatile("s_waitcnt vmcnt(12)\n\ts_barrier" ::: "memory")
#define WAITBAR6  asm volatile("s_waitcnt vmcnt(6)\n\ts_barrier" ::: "memory")
#define WAITBAR0  asm volatile("s_waitcnt vmcnt(0)\n\ts_barrier" ::: "memory")

// One K-step tc: read A(tc) frags from ring slot RING=tc%6, stage A(tc+3)
// into slot NXT=(tc+3)%6, 16 MFMA on b[BS] (BS=tc%3), prefetch B(tc+3) into
// b[BS] (just freed). E = step offset in current cursor window:
// A src = aQ + E*1024 (and -512), B src = bQ + E*2048. STG=0 in drain tail.
// Slot stride in shorts: 8 frags * 512 = 4096.
#define GEMM_STEP(RING, NXT, BS, STG, E)                                       \
  do {                                                                         \
    shortx8 aa[4];                                                             \
    _Pragma("unroll")                                                          \
    for (int s = 0; s < 4; ++s)                                                \
        aa[s] = *(const shortx8*)(aR + (RING) * 4096 + s * 512);               \
    if (STG) {                                                                 \
        GLOAD_LDS16(aQ + (E) * 1024,       aW + (NXT) * 4096);                 \
        GLOAD_LDS16(aQ + (E) * 1024 - 512, aW + (NXT) * 4096 + 512);           \
    }                                                                          \
    __builtin_amdgcn_s_setprio(1);                                             \
    _Pragma("unroll")                                                          \
    for (int s = 0; s < 4; ++s)                                                \
        _Pragma("unroll")                                                      \
        for (int dt = 0; dt < 4; ++dt)                                         \
            acc[s][dt] = __builtin_amdgcn_mfma_f32_16x16x32_bf16(              \
                aa[s], b[BS][dt], acc[s][dt], 0, 0, 0);                        \
    __builtin_amdgcn_s_setprio(0);                                             \
    if (STG) {                                                                 \
        _Pragma("unroll")                                                      \
        for (int dt = 0; dt < 4; ++dt)                                         \
            b[BS][dt] = *(const shortx8*)(bQ + (E) * 2048 + dt * 512);         \
    }                                                                          \
  } while (0)

__global__ __launch_bounds__(256, 3)
void gemm_pbv(const ushort* __restrict__ atile, const ushort* __restrict__ vbf,
              float* __restrict__ out) {
    __shared__ short As[6][8 * 512];   // 48 KB ring, 6 deep

    const int bid  = blockIdx.x;          // 0..767
    const int slot = bid >> 3;            // 0..95
    const int g    = (bid & 7) * 6 + (slot % 6);  // (h,bq) group 0..47
    const int nt   = slot / 6;            // 0..15
    const int h    = g >> 2;
    const int bq   = g & 3;
    const int tid  = threadIdx.x;
    const int wv   = tid >> 6;            // wave: sh = wv>>1, bw = wv&1
    const int lane = tid & 63;
    const int sh   = wv >> 1;
    const int bw   = wv & 1;
    const int bb   = bq * 2 + bw;

    floatx4 acc[4][4];
#pragma unroll
    for (int s = 0; s < 4; ++s)
#pragma unroll
        for (int dt = 0; dt < 4; ++dt) acc[s][dt] = (floatx4){0.f, 0.f, 0.f, 0.f};

    // A staging: wave wv stages frags fs = 2wv, 2wv+1.
    // cslot(tc, fs) = 2*tc - (nt*8 + fs) + 127   (always in [0,253])
    const ushort* aS = atile + ((size_t)h * NCSLOT + (127 - nt * 8 - 2 * wv)) * 512 + lane * 8;
    const ushort* bP = vbf + (size_t)(bb * NH + h) * (TSTEPS * 4 * 512) + lane * 8;
    short*       aW = &As[0][2 * wv * 512];                  // stage base, + slot*4096
    const short* aR = &As[0][sh * 4 * 512] + lane * 8;       // frag read,  + slot*4096

    shortx8 b[3][4];   // triple-buffered B (distance-3)

    // ---- prologue: three 6-op regions S(0), S(1), S(2), fenced apart
    GLOAD_LDS16(aS,       aW);
    GLOAD_LDS16(aS - 512, aW + 512);
#pragma unroll
    for (int dt = 0; dt < 4; ++dt) b[0][dt] = *(const shortx8*)(bP + dt * 512);
    FENCE;
    GLOAD_LDS16(aS + 1024, aW + 4096);
    GLOAD_LDS16(aS + 512,  aW + 4096 + 512);
#pragma unroll
    for (int dt = 0; dt < 4; ++dt) b[1][dt] = *(const shortx8*)(bP + 2048 + dt * 512);
    FENCE;
    GLOAD_LDS16(aS + 2048,       aW + 2 * 4096);
    GLOAD_LDS16(aS + 2048 - 512, aW + 2 * 4096 + 512);
#pragma unroll
    for (int dt = 0; dt < 4; ++dt) b[2][dt] = *(const shortx8*)(bP + 2 * 2048 + dt * 512);
    WAITBAR12;   // drains S(0): A(0) visible in LDS for all waves, B(0) in regs

    // cursors point at the S(tc+3) sources; at loop top (tc=6u): base = 6u+3
    const ushort* aQ = aS + 3 * 1024;
    const ushort* bQ = bP + 3 * 2048;

    // ---- main loop: tc = 0..59, period 6 = lcm(ring6, bbuf3)
    for (int u = 0; u < 10; ++u) {
        GEMM_STEP(0, 3, 0, 1, 0); WAITBAR12;
        GEMM_STEP(1, 4, 1, 1, 1); WAITBAR12;
        GEMM_STEP(2, 5, 2, 1, 2); WAITBAR12;
        GEMM_STEP(3, 0, 0, 1, 3); WAITBAR12;
        GEMM_STEP(4, 1, 1, 1, 4); WAITBAR12;
        GEMM_STEP(5, 2, 2, 1, 5); WAITBAR12;
        aQ += 6 * 1024;
        bQ += 6 * 2048;
    }
    // ---- tail: tc = 60..63 (cursor base = S(63) source; E=0 at tc=60)
    GEMM_STEP(0, 3, 0, 1, 0); WAITBAR12;   // tc=60: stages S(63); drains S(61)
    GEMM_STEP(1, 0, 1, 0, 0); WAITBAR6;    // tc=61: drain S(62)
    GEMM_STEP(2, 0, 2, 0, 0); WAITBAR0;    // tc=62: drain S(63)
    GEMM_STEP(3, 0, 0, 0, 0);              // tc=63: final compute

    // epilogue: D row=(lane>>4)*4+r (n-local), col=lane&15 (d-local)
    const int q    = lane >> 4;
    const int dcol = lane & 15;
    const int nB   = nt * 128 + sh * 64;
#pragma unroll
    for (int s = 0; s < 4; ++s) {
        int nsb = nB + s * 16 + q * 4;
#pragma unroll
        for (int r = 0; r < 4; ++r) {
            int n = nsb + r;
            if (n < SEQ) {
                float* ob = out + ((size_t)(bb * MAXPOS + 1 + n) * NH + h) * HD + dcol;
#pragma unroll
                for (int dt = 0; dt < 4; ++dt) ob[dt * 16] = acc[s][dt][r];
            }
        }
    }
}

extern "C" void kernel_launch(void* const* d_in, const int* in_sizes, int n_in,
                              void* d_out, int out_size, void* d_ws, size_t ws_size,
                              hipStream_t stream) {
    const float* v   = (const float*)d_in[0];  // (8, 2048, 12, 64)
    const float* off = (const float*)d_in[1];  // (1, 12)
    const float* w   = (const float*)d_in[2];  // (1, 12, 2046)
    float* out = (float*)d_out;

    ushort* atile = (ushort*)d_ws;
    ushort* vbf   = (ushort*)((char*)d_ws + ATILE_BYTES);

    prep_all<<<NB_V + NB_ZPB + NB_A + 48, 256, 0, stream>>>(v, w, off, atile, vbf, out);
    gemm_pbv<<<768, 256, 0, stream>>>(atile, vbf, out);
}

// Round 5
// 137.305 us; speedup vs baseline: 1.1028x; 1.0566x over previous
//
#include <hip/hip_runtime.h>
#include <hip/hip_bf16.h>

#define BATCH 8
#define MAXPOS 2048
#define SEQ 2046
#define NH 12
#define HD 64
#define NCSLOT 254      // ci = c/16 in [-127,126], cslot = ci+127
#define TSTEPS 64       // K-chunks of 32 covering t=0..2047 (zero-padded past 2045)
#define PLANE (NH * HD) // 768

typedef __attribute__((ext_vector_type(4))) float floatx4;
typedef __attribute__((ext_vector_type(8))) short shortx8;

// ws layout: [Atile: 12*254*512 bf16 = 3,121,152 B][Vbf: 8*12*256*512 bf16 = 25,165,824 B]
#define ATILE_BYTES (NH * NCSLOT * 512 * 2)

#define GLOAD_LDS16(src, dst)                                                  \
    __builtin_amdgcn_global_load_lds(                                          \
        (const __attribute__((address_space(1))) void*)(src),                  \
        (__attribute__((address_space(3))) void*)(dst), 16, 0, 0)

// Block ranges inside prep_all
#define NB_V   (TSTEPS * NH * BATCH)   // 6144
#define NB_ZPB NH                      // 12
#define NB_A   (NCSLOT * NH)           // 3048

// ---------------------------------------------------------------------------
// prep_all: single prologue kernel (UNCHANGED).
// ---------------------------------------------------------------------------
__global__ __launch_bounds__(256)
void prep_all(const float* __restrict__ v, const float* __restrict__ w,
              const float* __restrict__ off, ushort* __restrict__ atile,
              ushort* __restrict__ vbf, float* __restrict__ out) {
    const int bi  = blockIdx.x;
    const int tid = threadIdx.x;

    if (bi < NB_V) {
        // ---- prep_V: block = (tc,h,b); col-swizzle (key=q*16) kills 4-way conflict
        __shared__ float Ls[32][64];
        const int tc = bi & 63;
        int rem = bi >> 6;
        const int h = rem % NH;
        const int b = rem / NH;
#pragma unroll
        for (int i = 0; i < 2; ++i) {
            int idx = tid + 256 * i;
            int row = idx >> 4;
            int c4  = (idx & 15) * 4;
            int key = (row >> 3) * 16;
            int t   = tc * 32 + row;
            float4 val = make_float4(0.f, 0.f, 0.f, 0.f);
            if (t < SEQ) val = *(const float4*)(v + ((size_t)(b * MAXPOS + 1 + t) * NH + h) * HD + c4);
            *(float4*)&Ls[row][c4 ^ key] = val;
        }
        __syncthreads();
        const int wv   = tid >> 6;
        const int lane = tid & 63;
        const int q    = lane >> 4;
        const int dcol = lane & 15;
        ushort pk[8];
#pragma unroll
        for (int j = 0; j < 8; ++j) {
            __hip_bfloat16 bv = __float2bfloat16(Ls[q * 8 + j][(wv * 16 + dcol) ^ (q * 16)]);
            pk[j] = *(ushort*)&bv;
        }
        *(uint4*)(vbf + ((size_t)((b * NH + h) * TSTEPS + tc) * 4 + wv) * 512 + lane * 8) = *(uint4*)pk;
    } else if (bi < NB_V + NB_ZPB) {
        // ---- zpb scan
        __shared__ float Es[SEQ];
        __shared__ float Ss[SEQ];
        __shared__ float wsum[4];
        const int h    = bi - NB_V;
        const int wid  = tid >> 6;
        const int lane = tid & 63;
        const float offh = off[h];
        const float* wh  = w + h * SEQ;
        for (int i = tid; i < SEQ; i += 256) Es[i] = __expf(wh[i] - offh);
        __syncthreads();
        const int base = tid * 8;
        float loc[8];
        float s = 0.f;
#pragma unroll
        for (int j = 0; j < 8; ++j) {
            float e = (base + j < SEQ) ? Es[base + j] : 0.f;
            s += e; loc[j] = s;
        }
        float sc = s;
#pragma unroll
        for (int d = 1; d < 64; d <<= 1) {
            float t = __shfl_up(sc, d);
            if (lane >= d) sc += t;
        }
        if (lane == 63) wsum[wid] = sc;
        __syncthreads();
        float woff = 0.f;
        for (int k = 0; k < wid; ++k) woff += wsum[k];
        float prefix = woff + sc - s;
#pragma unroll
        for (int j = 0; j < 8; ++j)
            if (base + j < SEQ) Ss[base + j] = prefix + loc[j];
        __syncthreads();
        const float E0 = Es[0];
        const size_t zb = (size_t)BATCH * MAXPOS * PLANE;
        for (int i = tid; i < SEQ; i += 256)
            out[zb + (size_t)(i + 1) * NH + h] = Ss[i] + Ss[SEQ - 1 - i] - E0;
    } else if (bi < NB_V + NB_ZPB + NB_A) {
        // ---- prep_A: tile (h,cslot) elem[lane][j]=exp(w[h,|16ci+(lane>>4)*8-(lane&15)+j|]-off)
        const int idx   = bi - NB_V - NB_ZPB;
        const int cslot = idx % NCSLOT;
        const int h     = idx / NCSLOT;
        const float offh = off[h];
        const float* wh  = w + h * SEQ;
        const int ci   = cslot - 127;
        const int lane = tid >> 2;
        const int jp   = (tid & 3) * 2;
        const int q    = lane >> 4;
        const int m    = lane & 15;
        const int d0   = 16 * ci + q * 8 - m + jp;
        ushort pk[2];
#pragma unroll
        for (int e = 0; e < 2; ++e) {
            int k = d0 + e; k = (k < 0) ? -k : k;
            float val = (k < SEQ) ? __expf(wh[k] - offh) : 0.f;
            __hip_bfloat16 bv = __float2bfloat16(val);
            pk[e] = *(ushort*)&bv;
        }
        *(ushort2*)(atile + ((size_t)(h * NCSLOT + cslot) * 512 + lane * 8 + jp)) = *(ushort2*)pk;
    } else {
        // ---- zero boundary positions (p=0, p=2047) of both outputs
        const int i = (bi - NB_V - NB_ZPB - NB_A) * 256 + tid;
        if (i < 2 * BATCH * PLANE) {
            int side = i / (BATCH * PLANE);
            int r    = i % (BATCH * PLANE);
            int b    = r / PLANE;
            int j    = r % PLANE;
            int p    = side ? (MAXPOS - 1) : 0;
            out[((size_t)b * MAXPOS + p) * PLANE + j] = 0.f;
        }
        if (i < 2 * NH) {
            size_t zb = (size_t)BATCH * MAXPOS * PLANE;
            int p = (i < NH) ? 0 : (MAXPOS - 1);
            out[zb + (size_t)p * NH + (i % NH)] = 0.f;
        }
    }
}

// ---------------------------------------------------------------------------
// gemm_pbv (R5): TRAFFIC-CUT restructure. Theory: R1/R4 were L2-BW-bound
// (72 KB/step/CU = 64% of the 34.5 TB/s L2 ceiling); latency depth was a
// proven null (R4). This version cuts vector-memory traffic 4x:
//   Block = 256n x 64d x 1 batch (4 waves, each 64 rows of the SAME bb).
//   A: Toeplitz SLIDING WINDOW in LDS, ring-32 over cslot (32 KB). The
//      16-frag window shifts by 2 cslots/step -> stage only 2 NEW frags
//      (2 KB) per step (waves 0,1), vs 8 KB with 4x re-fetch before.
//   B: all 4 waves share one (bb,h) B-panel -> stage 4 frags (4 KB) per
//      step into LDS ring-4 (16 KB), one gload_lds per wave, read back
//      with ds_read_b128 (same lane-linear layout as the old reg loads).
//   Per-step per-block traffic 24 KB -> 6 KB. Per-wave VMEM: wv0,1 = 2
//   (A+B), wv2,3 = 1 (B); counted per-wave waits vmcnt(2)/vmcnt(1) at
//   distance 2 (stage S(t+2) at step t; drained end of t+1; read at t+2).
//   WAR: B slot (t+2)&3 last read at t-2 -> 2 barriers; A ring slot reuse
//   ~6 steps after last read. Cross-wave visibility: own-stage drained by
//   own vmcnt before the shared barrier (same protocol as R1/R4).
//   XCD swizzle: all 8 nt-blocks of one (h,bb) panel land on ONE XCD ->
//   panel (256 KB) + atile slices stay L2-resident per XCD.
// LDS 48 KB -> 3 blocks/CU (144 KB). Same epilogue mapping, nB=nt*256+wv*64.
// ---------------------------------------------------------------------------

#define WBAR                                                                   \
  do {                                                                         \
    if (wvu < 2) asm volatile("s_waitcnt vmcnt(2)\n\ts_barrier" ::: "memory"); \
    else         asm volatile("s_waitcnt vmcnt(1)\n\ts_barrier" ::: "memory"); \
  } while (0)
#define WBAR0 asm volatile("s_waitcnt vmcnt(0)\n\ts_barrier" ::: "memory")

// One K-step tc (T4 = tc&3 static, E = step offset in current 4-step window).
// Reads: A frags k=0..3 from ring slots (ab+2E-k)&31; B frags dt=0..3 from
// Bs[T4]. Stages (if STG): A cslot csw+2E -> ring slot (csw+2E)&31 (wv<2),
// B step tc+2 frag wvu -> Bs[(T4+2)&3][wvu]. Then 16 MFMA under setprio.
#define STEP(T4, E, STG)                                                       \
  do {                                                                         \
    shortx8 aa[4], bf[4];                                                      \
    const int abE = ab + 2 * (E);                                              \
    _Pragma("unroll")                                                          \
    for (int k = 0; k < 4; ++k)                                                \
        aa[k] = *(const shortx8*)(&As[(abE - k) & 31][lane8]);                 \
    _Pragma("unroll")                                                          \
    for (int dt = 0; dt < 4; ++dt)                                             \
        bf[dt] = *(const shortx8*)(&Bs[T4][dt][lane8]);                        \
    if (STG) {                                                                 \
        if (wvu < 2)                                                           \
            GLOAD_LDS16(aSt + (E) * 1024, &As[(csw + 2 * (E)) & 31][0]);       \
        GLOAD_LDS16(bSt + (E) * 2048, &Bs[((T4) + 2) & 3][wvu][0]);            \
    }                                                                          \
    __builtin_amdgcn_s_setprio(1);                                             \
    _Pragma("unroll")                                                          \
    for (int s = 0; s < 4; ++s)                                                \
        _Pragma("unroll")                                                      \
        for (int dt = 0; dt < 4; ++dt)                                         \
            acc[s][dt] = __builtin_amdgcn_mfma_f32_16x16x32_bf16(              \
                aa[s], bf[dt], acc[s][dt], 0, 0, 0);                           \
    __builtin_amdgcn_s_setprio(0);                                             \
  } while (0)

__global__ __launch_bounds__(256, 3)
void gemm_pbv(const ushort* __restrict__ atile, const ushort* __restrict__ vbf,
              float* __restrict__ out) {
    __shared__ short As[32][512];    // 32 KB: A sliding window, ring-32 over cslot
    __shared__ short Bs[4][4][512];  // 16 KB: B ring-4 (4 frags/step)

    const int bid  = blockIdx.x;               // 0..767
    const int l    = (bid & 7) * 96 + (bid >> 3);  // XCD-contiguous logical id
    const int g    = l >> 3;                   // (h,bb) group 0..95
    const int nt   = l & 7;                    // 256-row tile 0..7
    const int h    = g >> 3;                   // 0..11
    const int bb   = g & 7;                    // 0..7
    const int tid  = threadIdx.x;
    const int wvu  = __builtin_amdgcn_readfirstlane(tid >> 6);  // wave id (SGPR)
    const int lane = tid & 63;
    const int lane8 = lane * 8;
    const int nt16  = nt * 16;

    floatx4 acc[4][4];
#pragma unroll
    for (int s = 0; s < 4; ++s)
#pragma unroll
        for (int dt = 0; dt < 4; ++dt) acc[s][dt] = (floatx4){0.f, 0.f, 0.f, 0.f};

    const ushort* aBase  = atile + (size_t)h * NCSLOT * 512;
    const ushort* bPanel = vbf + (size_t)(bb * NH + h) * (TSTEPS * 4 * 512);

    // ---- prologue: A window cslots [112-nt16 .. 129-nt16] (18 frags,
    // covers reads of steps 0 and 1) + B(0), B(1). All drained once.
    {
        const int cbase = 112 - nt16;   // >= 0 (nt<=7)
        const int j0 = (wvu == 0) ? 0 : (wvu == 1) ? 5 : (wvu == 2) ? 10 : 14;
        const int j1 = (wvu == 0) ? 5 : (wvu == 1) ? 10 : (wvu == 2) ? 14 : 18;
        for (int j = j0; j < j1; ++j) {
            const int cs = cbase + j;
            GLOAD_LDS16(aBase + (size_t)cs * 512 + lane8, &As[cs & 31][0]);
        }
        GLOAD_LDS16(bPanel + (0 * 4 + wvu) * 512 + lane8, &Bs[0][wvu][0]);
        GLOAD_LDS16(bPanel + (1 * 4 + wvu) * 512 + lane8, &Bs[1][wvu][0]);
    }
    WBAR0;   // everything for steps 0,1 resident

    // A read cursor: frag k at step tc lives at ring slot (2tc+C0-k)&31,
    // C0 = 127-nt16-4wv. A stage cursor (wv<2): cslot csw = 131-nt16-wv+2tc.
    int ab  = 127 - nt16 - 4 * wvu;
    int csw = 131 - nt16 - wvu;
    const ushort* aSt = aBase + (size_t)(131 - nt16 - wvu) * 512 + lane8;
    const ushort* bSt = bPanel + (2 * 4 + wvu) * 512 + lane8;

    // ---- main loop: tc = 0..59 (15 x 4 steps), staging S(tc+2)
    for (int u = 0; u < 15; ++u) {
        STEP(0, 0, 1); WBAR;
        STEP(1, 1, 1); WBAR;
        STEP(2, 2, 1); WBAR;
        STEP(3, 3, 1); WBAR;
        ab += 8; csw += 8; aSt += 4 * 1024; bSt += 4 * 2048;
    }
    // ---- tail: tc = 60..63
    STEP(0, 0, 1); WBAR;    // tc=60: stages S(62)
    STEP(1, 1, 1); WBAR;    // tc=61: stages S(63)
    STEP(2, 2, 0); WBAR0;   // tc=62: drain S(63)
    STEP(3, 3, 0);          // tc=63: final compute

    // epilogue: D row=(lane>>4)*4+r (n-local), col=lane&15 (d-local)
    const int q    = lane >> 4;
    const int dcol = lane & 15;
    const int nB   = nt * 256 + wvu * 64;
#pragma unroll
    for (int s = 0; s < 4; ++s) {
        int nsb = nB + s * 16 + q * 4;
#pragma unroll
        for (int r = 0; r < 4; ++r) {
            int n = nsb + r;
            if (n < SEQ) {
                float* ob = out + ((size_t)(bb * MAXPOS + 1 + n) * NH + h) * HD + dcol;
#pragma unroll
                for (int dt = 0; dt < 4; ++dt) ob[dt * 16] = acc[s][dt][r];
            }
        }
    }
}

extern "C" void kernel_launch(void* const* d_in, const int* in_sizes, int n_in,
                              void* d_out, int out_size, void* d_ws, size_t ws_size,
                              hipStream_t stream) {
    const float* v   = (const float*)d_in[0];  // (8, 2048, 12, 64)
    const float* off = (const float*)d_in[1];  // (1, 12)
    const float* w   = (const float*)d_in[2];  // (1, 12, 2046)
    float* out = (float*)d_out;

    ushort* atile = (ushort*)d_ws;
    ushort* vbf   = (ushort*)((char*)d_ws + ATILE_BYTES);

    prep_all<<<NB_V + NB_ZPB + NB_A + 48, 256, 0, stream>>>(v, w, off, atile, vbf, out);
    gemm_pbv<<<768, 256, 0, stream>>>(atile, vbf, out);
}

// Round 6
// 136.121 us; speedup vs baseline: 1.1124x; 1.0087x over previous
//
#include <hip/hip_runtime.h>
#include <hip/hip_bf16.h>

#define BATCH 8
#define MAXPOS 2048
#define SEQ 2046
#define NH 12
#define HD 64
#define NCSLOT 254      // ci = c/16 in [-127,126], cslot = ci+127
#define TSTEPS 64       // K-chunks of 32 covering t=0..2047 (zero-padded past 2045)
#define PLANE (NH * HD) // 768

typedef __attribute__((ext_vector_type(4))) float floatx4;
typedef __attribute__((ext_vector_type(8))) short shortx8;

// ws layout: [Atile: 12*254*512 bf16 = 3,121,152 B][Vbf: 8*12*256*512 bf16 = 25,165,824 B]
#define ATILE_BYTES (NH * NCSLOT * 512 * 2)

#define GLOAD_LDS16(src, dst)                                                  \
    __builtin_amdgcn_global_load_lds(                                          \
        (const __attribute__((address_space(1))) void*)(src),                  \
        (__attribute__((address_space(3))) void*)(dst), 16, 0, 0)

// Block ranges inside prep_all
#define NB_V   (TSTEPS * NH * BATCH)   // 6144
#define NB_ZPB NH                      // 12
#define NB_A   (NCSLOT * NH)           // 3048

// ---------------------------------------------------------------------------
// prep_all: single prologue kernel (UNCHANGED).
// ---------------------------------------------------------------------------
__global__ __launch_bounds__(256)
void prep_all(const float* __restrict__ v, const float* __restrict__ w,
              const float* __restrict__ off, ushort* __restrict__ atile,
              ushort* __restrict__ vbf, float* __restrict__ out) {
    const int bi  = blockIdx.x;
    const int tid = threadIdx.x;

    if (bi < NB_V) {
        // ---- prep_V: block = (tc,h,b); col-swizzle (key=q*16) kills 4-way conflict
        __shared__ float Ls[32][64];
        const int tc = bi & 63;
        int rem = bi >> 6;
        const int h = rem % NH;
        const int b = rem / NH;
#pragma unroll
        for (int i = 0; i < 2; ++i) {
            int idx = tid + 256 * i;
            int row = idx >> 4;
            int c4  = (idx & 15) * 4;
            int key = (row >> 3) * 16;
            int t   = tc * 32 + row;
            float4 val = make_float4(0.f, 0.f, 0.f, 0.f);
            if (t < SEQ) val = *(const float4*)(v + ((size_t)(b * MAXPOS + 1 + t) * NH + h) * HD + c4);
            *(float4*)&Ls[row][c4 ^ key] = val;
        }
        __syncthreads();
        const int wv   = tid >> 6;
        const int lane = tid & 63;
        const int q    = lane >> 4;
        const int dcol = lane & 15;
        ushort pk[8];
#pragma unroll
        for (int j = 0; j < 8; ++j) {
            __hip_bfloat16 bv = __float2bfloat16(Ls[q * 8 + j][(wv * 16 + dcol) ^ (q * 16)]);
            pk[j] = *(ushort*)&bv;
        }
        *(uint4*)(vbf + ((size_t)((b * NH + h) * TSTEPS + tc) * 4 + wv) * 512 + lane * 8) = *(uint4*)pk;
    } else if (bi < NB_V + NB_ZPB) {
        // ---- zpb scan
        __shared__ float Es[SEQ];
        __shared__ float Ss[SEQ];
        __shared__ float wsum[4];
        const int h    = bi - NB_V;
        const int wid  = tid >> 6;
        const int lane = tid & 63;
        const float offh = off[h];
        const float* wh  = w + h * SEQ;
        for (int i = tid; i < SEQ; i += 256) Es[i] = __expf(wh[i] - offh);
        __syncthreads();
        const int base = tid * 8;
        float loc[8];
        float s = 0.f;
#pragma unroll
        for (int j = 0; j < 8; ++j) {
            float e = (base + j < SEQ) ? Es[base + j] : 0.f;
            s += e; loc[j] = s;
        }
        float sc = s;
#pragma unroll
        for (int d = 1; d < 64; d <<= 1) {
            float t = __shfl_up(sc, d);
            if (lane >= d) sc += t;
        }
        if (lane == 63) wsum[wid] = sc;
        __syncthreads();
        float woff = 0.f;
        for (int k = 0; k < wid; ++k) woff += wsum[k];
        float prefix = woff + sc - s;
#pragma unroll
        for (int j = 0; j < 8; ++j)
            if (base + j < SEQ) Ss[base + j] = prefix + loc[j];
        __syncthreads();
        const float E0 = Es[0];
        const size_t zb = (size_t)BATCH * MAXPOS * PLANE;
        for (int i = tid; i < SEQ; i += 256)
            out[zb + (size_t)(i + 1) * NH + h] = Ss[i] + Ss[SEQ - 1 - i] - E0;
    } else if (bi < NB_V + NB_ZPB + NB_A) {
        // ---- prep_A: tile (h,cslot) elem[lane][j]=exp(w[h,|16ci+(lane>>4)*8-(lane&15)+j|]-off)
        const int idx   = bi - NB_V - NB_ZPB;
        const int cslot = idx % NCSLOT;
        const int h     = idx / NCSLOT;
        const float offh = off[h];
        const float* wh  = w + h * SEQ;
        const int ci   = cslot - 127;
        const int lane = tid >> 2;
        const int jp   = (tid & 3) * 2;
        const int q    = lane >> 4;
        const int m    = lane & 15;
        const int d0   = 16 * ci + q * 8 - m + jp;
        ushort pk[2];
#pragma unroll
        for (int e = 0; e < 2; ++e) {
            int k = d0 + e; k = (k < 0) ? -k : k;
            float val = (k < SEQ) ? __expf(wh[k] - offh) : 0.f;
            __hip_bfloat16 bv = __float2bfloat16(val);
            pk[e] = *(ushort*)&bv;
        }
        *(ushort2*)(atile + ((size_t)(h * NCSLOT + cslot) * 512 + lane * 8 + jp)) = *(ushort2*)pk;
    } else {
        // ---- zero boundary positions (p=0, p=2047) of both outputs
        const int i = (bi - NB_V - NB_ZPB - NB_A) * 256 + tid;
        if (i < 2 * BATCH * PLANE) {
            int side = i / (BATCH * PLANE);
            int r    = i % (BATCH * PLANE);
            int b    = r / PLANE;
            int j    = r % PLANE;
            int p    = side ? (MAXPOS - 1) : 0;
            out[((size_t)b * MAXPOS + p) * PLANE + j] = 0.f;
        }
        if (i < 2 * NH) {
            size_t zb = (size_t)BATCH * MAXPOS * PLANE;
            int p = (i < NH) ? 0 : (MAXPOS - 1);
            out[zb + (size_t)p * NH + (i % NH)] = 0.f;
        }
    }
}

// ---------------------------------------------------------------------------
// gemm_pbv (R6): R5 structure + TOEPLITZ REGISTER ROTATION for A.
//   The A frag for subtile s at step tc (cslot = 2tc-(base+s)+127) equals the
//   frag subtile s-2 consumed at step tc-1. So the 4 A frags live in VGPRs
//   across steps: per step, rotate a2<-a0, a3<-a1 and ds_read only the 2 NEW
//   frags (ring slots ab+2tc, ab+2tc-1). A LDS reads per wave per step: 4->2;
//   per-CU LDS read traffic 96->72 KB/step (-25%) -- attacking the LDS read
//   port, which the R5 numbers indicate is now the busiest pipe (MfmaUtil
//   46% with zero bank conflicts and quiet VMEM).
//   MFMA order: s=2,3 first (operands already in registers), s=0,1 last so
//   the fresh ds_reads hide under 8 MFMAs.
//   Everything else UNCHANGED from R5: sliding A window ring-32 (stage 2
//   frags/step by waves 0,1), B via LDS ring-4 (1 gload_lds per wave),
//   counted per-wave waits vmcnt(2)/vmcnt(1) + s_barrier per step, distance
//   2, XCD swizzle, 48 KB LDS, 3 blocks/CU.
// ---------------------------------------------------------------------------

#define WBAR                                                                   \
  do {                                                                         \
    if (wvu < 2) asm volatile("s_waitcnt vmcnt(2)\n\ts_barrier" ::: "memory"); \
    else         asm volatile("s_waitcnt vmcnt(1)\n\ts_barrier" ::: "memory"); \
  } while (0)
#define WBAR0 asm volatile("s_waitcnt vmcnt(0)\n\ts_barrier" ::: "memory")

// One K-step tc (T4 = tc&3 static, E = step offset in current 4-step window).
// Rotate A regs (a2<-a0, a3<-a1), ds_read 2 new A frags + 4 B frags, stage
// (if STG) A cslot csw+2E (wv<2) and B step tc+2 frag wvu, then 16 MFMA
// under setprio, s=2,3 (reg-resident operands) before s=0,1 (fresh reads).
#define STEP(T4, E, STG)                                                       \
  do {                                                                         \
    const int abE = ab + 2 * (E);                                              \
    shortx8 bf[4];                                                             \
    a2 = a0; a3 = a1;                                                          \
    a0 = *(const shortx8*)(&As[(abE) & 31][lane8]);                            \
    a1 = *(const shortx8*)(&As[(abE - 1) & 31][lane8]);                        \
    _Pragma("unroll")                                                          \
    for (int dt = 0; dt < 4; ++dt)                                             \
        bf[dt] = *(const shortx8*)(&Bs[T4][dt][lane8]);                        \
    if (STG) {                                                                 \
        if (wvu < 2)                                                           \
            GLOAD_LDS16(aSt + (E) * 1024, &As[(csw + 2 * (E)) & 31][0]);       \
        GLOAD_LDS16(bSt + (E) * 2048, &Bs[((T4) + 2) & 3][wvu][0]);            \
    }                                                                          \
    __builtin_amdgcn_s_setprio(1);                                             \
    _Pragma("unroll")                                                          \
    for (int dt = 0; dt < 4; ++dt)                                             \
        acc[2][dt] = __builtin_amdgcn_mfma_f32_16x16x32_bf16(a2, bf[dt], acc[2][dt], 0, 0, 0); \
    _Pragma("unroll")                                                          \
    for (int dt = 0; dt < 4; ++dt)                                             \
        acc[3][dt] = __builtin_amdgcn_mfma_f32_16x16x32_bf16(a3, bf[dt], acc[3][dt], 0, 0, 0); \
    _Pragma("unroll")                                                          \
    for (int dt = 0; dt < 4; ++dt)                                             \
        acc[0][dt] = __builtin_amdgcn_mfma_f32_16x16x32_bf16(a0, bf[dt], acc[0][dt], 0, 0, 0); \
    _Pragma("unroll")                                                          \
    for (int dt = 0; dt < 4; ++dt)                                             \
        acc[1][dt] = __builtin_amdgcn_mfma_f32_16x16x32_bf16(a1, bf[dt], acc[1][dt], 0, 0, 0); \
    __builtin_amdgcn_s_setprio(0);                                             \
  } while (0)

__global__ __launch_bounds__(256, 3)
void gemm_pbv(const ushort* __restrict__ atile, const ushort* __restrict__ vbf,
              float* __restrict__ out) {
    __shared__ short As[32][512];    // 32 KB: A sliding window, ring-32 over cslot
    __shared__ short Bs[4][4][512];  // 16 KB: B ring-4 (4 frags/step)

    const int bid  = blockIdx.x;               // 0..767
    const int l    = (bid & 7) * 96 + (bid >> 3);  // XCD-contiguous logical id
    const int g    = l >> 3;                   // (h,bb) group 0..95
    const int nt   = l & 7;                    // 256-row tile 0..7
    const int h    = g >> 3;                   // 0..11
    const int bb   = g & 7;                    // 0..7
    const int tid  = threadIdx.x;
    const int wvu  = __builtin_amdgcn_readfirstlane(tid >> 6);  // wave id (SGPR)
    const int lane = tid & 63;
    const int lane8 = lane * 8;
    const int nt16  = nt * 16;

    floatx4 acc[4][4];
#pragma unroll
    for (int s = 0; s < 4; ++s)
#pragma unroll
        for (int dt = 0; dt < 4; ++dt) acc[s][dt] = (floatx4){0.f, 0.f, 0.f, 0.f};

    const ushort* aBase  = atile + (size_t)h * NCSLOT * 512;
    const ushort* bPanel = vbf + (size_t)(bb * NH + h) * (TSTEPS * 4 * 512);

    // ---- prologue: A window cslots [112-nt16 .. 129-nt16] (18 frags,
    // covers reads of steps 0 and 1 incl. rotation pre-seed) + B(0), B(1).
    {
        const int cbase = 112 - nt16;   // >= 0 (nt<=7)
        const int j0 = (wvu == 0) ? 0 : (wvu == 1) ? 5 : (wvu == 2) ? 10 : 14;
        const int j1 = (wvu == 0) ? 5 : (wvu == 1) ? 10 : (wvu == 2) ? 14 : 18;
        for (int j = j0; j < j1; ++j) {
            const int cs = cbase + j;
            GLOAD_LDS16(aBase + (size_t)cs * 512 + lane8, &As[cs & 31][0]);
        }
        GLOAD_LDS16(bPanel + (0 * 4 + wvu) * 512 + lane8, &Bs[0][wvu][0]);
        GLOAD_LDS16(bPanel + (1 * 4 + wvu) * 512 + lane8, &Bs[1][wvu][0]);
    }
    WBAR0;   // everything for steps 0,1 resident

    // A read cursor: frag for subtile s at step tc lives at ring slot
    // (2tc + C0 - s)&31, C0 = 127-nt16-4wv. Stage cursor (wv<2): cslot
    // csw = 131-nt16-wv+2tc.
    int ab  = 127 - nt16 - 4 * wvu;
    int csw = 131 - nt16 - wvu;
    const ushort* aSt = aBase + (size_t)(131 - nt16 - wvu) * 512 + lane8;
    const ushort* bSt = bPanel + (2 * 4 + wvu) * 512 + lane8;

    // rotation pre-seed: "previous a0,a1" = frags (ab-2),(ab-3) so that
    // step tc=0's rotate yields a2=slot(ab-2), a3=slot(ab-3).
    shortx8 a0, a1, a2, a3;
    a0 = *(const shortx8*)(&As[(ab - 2) & 31][lane8]);
    a1 = *(const shortx8*)(&As[(ab - 3) & 31][lane8]);

    // ---- main loop: tc = 0..59 (15 x 4 steps), staging S(tc+2)
    for (int u = 0; u < 15; ++u) {
        STEP(0, 0, 1); WBAR;
        STEP(1, 1, 1); WBAR;
        STEP(2, 2, 1); WBAR;
        STEP(3, 3, 1); WBAR;
        ab += 8; csw += 8; aSt += 4 * 1024; bSt += 4 * 2048;
    }
    // ---- tail: tc = 60..63
    STEP(0, 0, 1); WBAR;    // tc=60: stages S(62)
    STEP(1, 1, 1); WBAR;    // tc=61: stages S(63)
    STEP(2, 2, 0); WBAR0;   // tc=62: drain S(63)
    STEP(3, 3, 0);          // tc=63: final compute

    // epilogue: D row=(lane>>4)*4+r (n-local), col=lane&15 (d-local)
    const int q    = lane >> 4;
    const int dcol = lane & 15;
    const int nB   = nt * 256 + wvu * 64;
#pragma unroll
    for (int s = 0; s < 4; ++s) {
        int nsb = nB + s * 16 + q * 4;
#pragma unroll
        for (int r = 0; r < 4; ++r) {
            int n = nsb + r;
            if (n < SEQ) {
                float* ob = out + ((size_t)(bb * MAXPOS + 1 + n) * NH + h) * HD + dcol;
#pragma unroll
                for (int dt = 0; dt < 4; ++dt) ob[dt * 16] = acc[s][dt][r];
            }
        }
    }
}

extern "C" void kernel_launch(void* const* d_in, const int* in_sizes, int n_in,
                              void* d_out, int out_size, void* d_ws, size_t ws_size,
                              hipStream_t stream) {
    const float* v   = (const float*)d_in[0];  // (8, 2048, 12, 64)
    const float* off = (const float*)d_in[1];  // (1, 12)
    const float* w   = (const float*)d_in[2];  // (1, 12, 2046)
    float* out = (float*)d_out;

    ushort* atile = (ushort*)d_ws;
    ushort* vbf   = (ushort*)((char*)d_ws + ATILE_BYTES);

    prep_all<<<NB_V + NB_ZPB + NB_A + 48, 256, 0, stream>>>(v, w, off, atile, vbf, out);
    gemm_pbv<<<768, 256, 0, stream>>>(atile, vbf, out);
}

// Round 7
// 135.695 us; speedup vs baseline: 1.1159x; 1.0031x over previous
//
#include <hip/hip_runtime.h>
#include <hip/hip_bf16.h>

#define BATCH 8
#define MAXPOS 2048
#define SEQ 2046
#define NH 12
#define HD 64
#define NCSLOT 254      // ci = c/16 in [-127,126], cslot = ci+127
#define TSTEPS 64       // K-chunks of 32 covering t=0..2047 (zero-padded past 2045)
#define PLANE (NH * HD) // 768

typedef __attribute__((ext_vector_type(4))) float floatx4;
typedef __attribute__((ext_vector_type(8))) short shortx8;

// ws layout: [Atile: 12*254*512 bf16 = 3,121,152 B][Vbf: 8*12*256*512 bf16 = 25,165,824 B]
#define ATILE_BYTES (NH * NCSLOT * 512 * 2)

#define GLOAD_LDS16(src, dst)                                                  \
    __builtin_amdgcn_global_load_lds(                                          \
        (const __attribute__((address_space(1))) void*)(src),                  \
        (__attribute__((address_space(3))) void*)(dst), 16, 0, 0)

// Block ranges inside prep_all (R7: prep_V merged to one block per (b,tc))
#define NB_V2  (BATCH * TSTEPS)        // 512
#define NB_ZPB NH                      // 12
#define NB_A   (NCSLOT * NH)           // 3048

// ---------------------------------------------------------------------------
// prep_all (R7): prep_V REWRITTEN for contiguous reads.
//   [0,512)       prep_V : block=(b,tc). The 32 rows x 768 f32 of v for one
//                 (b,tc) are ONE contiguous 96 KB chunk -> 24 coalesced
//                 float4 loads/thread (24-deep MLP), bf16-convert into a
//                 48 KB LDS tile with the proven ^(row>>3)*16 column swizzle,
//                 then emit B-fragments for ALL 12 heads (output indexing
//                 bit-identical to the old per-(tc,h,b) kernel).
//                 Old version: 6144 blocks x 8 KB fragmented reads, ~30% of
//                 HBM BW. This: 512 blocks x 96 KB contiguous.
//   [512,524)     zpb    : unchanged logic (LDS via shared smem union)
//   [524,3572)    prep_A : unchanged
//   [3572,3620)   zeros  : unchanged
// All phases share one static 48 KB smem (union) so prep_A/zpb blocks can
// co-schedule with prep_V blocks in a single launch.
// ---------------------------------------------------------------------------
__global__ __launch_bounds__(256)
void prep_all(const float* __restrict__ v, const float* __restrict__ w,
              const float* __restrict__ off, ushort* __restrict__ atile,
              ushort* __restrict__ vbf, float* __restrict__ out) {
    __shared__ __align__(16) char smem[32 * 768 * 2];   // 48 KB, union'd per phase
    const int bi  = blockIdx.x;
    const int tid = threadIdx.x;

    if (bi < NB_V2) {
        // ---- prep_V: block = (b,tc); contiguous 96 KB read, 12-head emit
        ushort (*L)[768] = (ushort(*)[768])smem;
        const int b  = bi >> 6;
        const int tc = bi & 63;
        const int t0 = tc * 32;
        const float* vb = v + (size_t)(b * MAXPOS + 1 + t0) * PLANE;
#pragma unroll
        for (int i = 0; i < 24; ++i) {
            const int f = i * 256 + tid;    // float4 index in [0,6144)
            const int r = f / 192;          // row 0..31
            const int s = f - r * 192;      // float4 within row
            float4 val = make_float4(0.f, 0.f, 0.f, 0.f);
            if (t0 + r < SEQ) val = *(const float4*)(vb + (size_t)f * 4);
            __hip_bfloat16 c0 = __float2bfloat16(val.x);
            __hip_bfloat16 c1 = __float2bfloat16(val.y);
            __hip_bfloat16 c2 = __float2bfloat16(val.z);
            __hip_bfloat16 c3 = __float2bfloat16(val.w);
            ushort4 pk;
            pk.x = *(ushort*)&c0; pk.y = *(ushort*)&c1;
            pk.z = *(ushort*)&c2; pk.w = *(ushort*)&c3;
            // column swizzle ^ (r>>3)*16 (bits 4-5) keeps stage-2 conflict-free
            *(ushort4*)&L[r][(s * 4) ^ ((r >> 3) * 16)] = pk;
        }
        __syncthreads();
        const int wv   = tid >> 6;
        const int lane = tid & 63;
        const int q    = lane >> 4;
        const int dcol = lane & 15;
        const int cb   = wv * 16 + dcol;
#pragma unroll
        for (int h = 0; h < NH; ++h) {
            const int pc = (h * 64 + cb) ^ (q * 16);  // q*16 toggles bits 4-5 only
            ushort pk[8];
#pragma unroll
            for (int j = 0; j < 8; ++j) pk[j] = L[q * 8 + j][pc];
            *(uint4*)(vbf + ((size_t)((b * NH + h) * TSTEPS + tc) * 4 + wv) * 512 + lane * 8) = *(uint4*)pk;
        }
    } else if (bi < NB_V2 + NB_ZPB) {
        // ---- zpb scan (logic unchanged; LDS from smem union)
        float* Es   = (float*)smem;          // SEQ floats
        float* Ss   = (float*)smem + 2048;   // SEQ floats
        float* wsum = (float*)smem + 4096;   // 4 floats
        const int h    = bi - NB_V2;
        const int wid  = tid >> 6;
        const int lane = tid & 63;
        const float offh = off[h];
        const float* wh  = w + h * SEQ;
        for (int i = tid; i < SEQ; i += 256) Es[i] = __expf(wh[i] - offh);
        __syncthreads();
        const int base = tid * 8;
        float loc[8];
        float s = 0.f;
#pragma unroll
        for (int j = 0; j < 8; ++j) {
            float e = (base + j < SEQ) ? Es[base + j] : 0.f;
            s += e; loc[j] = s;
        }
        float sc = s;
#pragma unroll
        for (int d = 1; d < 64; d <<= 1) {
            float t = __shfl_up(sc, d);
            if (lane >= d) sc += t;
        }
        if (lane == 63) wsum[wid] = sc;
        __syncthreads();
        float woff = 0.f;
        for (int k = 0; k < wid; ++k) woff += wsum[k];
        float prefix = woff + sc - s;
#pragma unroll
        for (int j = 0; j < 8; ++j)
            if (base + j < SEQ) Ss[base + j] = prefix + loc[j];
        __syncthreads();
        const float E0 = Es[0];
        const size_t zb = (size_t)BATCH * MAXPOS * PLANE;
        for (int i = tid; i < SEQ; i += 256)
            out[zb + (size_t)(i + 1) * NH + h] = Ss[i] + Ss[SEQ - 1 - i] - E0;
    } else if (bi < NB_V2 + NB_ZPB + NB_A) {
        // ---- prep_A: tile (h,cslot) elem[lane][j]=exp(w[h,|16ci+(lane>>4)*8-(lane&15)+j|]-off)
        const int idx   = bi - NB_V2 - NB_ZPB;
        const int cslot = idx % NCSLOT;
        const int h     = idx / NCSLOT;
        const float offh = off[h];
        const float* wh  = w + h * SEQ;
        const int ci   = cslot - 127;
        const int lane = tid >> 2;
        const int jp   = (tid & 3) * 2;
        const int q    = lane >> 4;
        const int m    = lane & 15;
        const int d0   = 16 * ci + q * 8 - m + jp;
        ushort pk[2];
#pragma unroll
        for (int e = 0; e < 2; ++e) {
            int k = d0 + e; k = (k < 0) ? -k : k;
            float val = (k < SEQ) ? __expf(wh[k] - offh) : 0.f;
            __hip_bfloat16 bv = __float2bfloat16(val);
            pk[e] = *(ushort*)&bv;
        }
        *(ushort2*)(atile + ((size_t)(h * NCSLOT + cslot) * 512 + lane * 8 + jp)) = *(ushort2*)pk;
    } else {
        // ---- zero boundary positions (p=0, p=2047) of both outputs
        const int i = (bi - NB_V2 - NB_ZPB - NB_A) * 256 + tid;
        if (i < 2 * BATCH * PLANE) {
            int side = i / (BATCH * PLANE);
            int r    = i % (BATCH * PLANE);
            int b    = r / PLANE;
            int j    = r % PLANE;
            int p    = side ? (MAXPOS - 1) : 0;
            out[((size_t)b * MAXPOS + p) * PLANE + j] = 0.f;
        }
        if (i < 2 * NH) {
            size_t zb = (size_t)BATCH * MAXPOS * PLANE;
            int p = (i < NH) ? 0 : (MAXPOS - 1);
            out[zb + (size_t)p * NH + (i % NH)] = 0.f;
        }
    }
}

// ---------------------------------------------------------------------------
// gemm_pbv (R6, UNCHANGED this round — control for attribution):
// R5 structure + Toeplitz register rotation for A. See R6 notes.
// ---------------------------------------------------------------------------

#define WBAR                                                                   \
  do {                                                                         \
    if (wvu < 2) asm volatile("s_waitcnt vmcnt(2)\n\ts_barrier" ::: "memory"); \
    else         asm volatile("s_waitcnt vmcnt(1)\n\ts_barrier" ::: "memory"); \
  } while (0)
#define WBAR0 asm volatile("s_waitcnt vmcnt(0)\n\ts_barrier" ::: "memory")

#define STEP(T4, E, STG)                                                       \
  do {                                                                         \
    const int abE = ab + 2 * (E);                                              \
    shortx8 bf[4];                                                             \
    a2 = a0; a3 = a1;                                                          \
    a0 = *(const shortx8*)(&As[(abE) & 31][lane8]);                            \
    a1 = *(const shortx8*)(&As[(abE - 1) & 31][lane8]);                        \
    _Pragma("unroll")                                                          \
    for (int dt = 0; dt < 4; ++dt)                                             \
        bf[dt] = *(const shortx8*)(&Bs[T4][dt][lane8]);                        \
    if (STG) {                                                                 \
        if (wvu < 2)                                                           \
            GLOAD_LDS16(aSt + (E) * 1024, &As[(csw + 2 * (E)) & 31][0]);       \
        GLOAD_LDS16(bSt + (E) * 2048, &Bs[((T4) + 2) & 3][wvu][0]);            \
    }                                                                          \
    __builtin_amdgcn_s_setprio(1);                                             \
    _Pragma("unroll")                                                          \
    for (int dt = 0; dt < 4; ++dt)                                             \
        acc[2][dt] = __builtin_amdgcn_mfma_f32_16x16x32_bf16(a2, bf[dt], acc[2][dt], 0, 0, 0); \
    _Pragma("unroll")                                                          \
    for (int dt = 0; dt < 4; ++dt)                                             \
        acc[3][dt] = __builtin_amdgcn_mfma_f32_16x16x32_bf16(a3, bf[dt], acc[3][dt], 0, 0, 0); \
    _Pragma("unroll")                                                          \
    for (int dt = 0; dt < 4; ++dt)                                             \
        acc[0][dt] = __builtin_amdgcn_mfma_f32_16x16x32_bf16(a0, bf[dt], acc[0][dt], 0, 0, 0); \
    _Pragma("unroll")                                                          \
    for (int dt = 0; dt < 4; ++dt)                                             \
        acc[1][dt] = __builtin_amdgcn_mfma_f32_16x16x32_bf16(a1, bf[dt], acc[1][dt], 0, 0, 0); \
    __builtin_amdgcn_s_setprio(0);                                             \
  } while (0)

__global__ __launch_bounds__(256, 3)
void gemm_pbv(const ushort* __restrict__ atile, const ushort* __restrict__ vbf,
              float* __restrict__ out) {
    __shared__ short As[32][512];    // 32 KB: A sliding window, ring-32 over cslot
    __shared__ short Bs[4][4][512];  // 16 KB: B ring-4 (4 frags/step)

    const int bid  = blockIdx.x;               // 0..767
    const int l    = (bid & 7) * 96 + (bid >> 3);  // XCD-contiguous logical id
    const int g    = l >> 3;                   // (h,bb) group 0..95
    const int nt   = l & 7;                    // 256-row tile 0..7
    const int h    = g >> 3;                   // 0..11
    const int bb   = g & 7;                    // 0..7
    const int tid  = threadIdx.x;
    const int wvu  = __builtin_amdgcn_readfirstlane(tid >> 6);  // wave id (SGPR)
    const int lane = tid & 63;
    const int lane8 = lane * 8;
    const int nt16  = nt * 16;

    floatx4 acc[4][4];
#pragma unroll
    for (int s = 0; s < 4; ++s)
#pragma unroll
        for (int dt = 0; dt < 4; ++dt) acc[s][dt] = (floatx4){0.f, 0.f, 0.f, 0.f};

    const ushort* aBase  = atile + (size_t)h * NCSLOT * 512;
    const ushort* bPanel = vbf + (size_t)(bb * NH + h) * (TSTEPS * 4 * 512);

    // ---- prologue: A window cslots [112-nt16 .. 129-nt16] + B(0), B(1)
    {
        const int cbase = 112 - nt16;   // >= 0 (nt<=7)
        const int j0 = (wvu == 0) ? 0 : (wvu == 1) ? 5 : (wvu == 2) ? 10 : 14;
        const int j1 = (wvu == 0) ? 5 : (wvu == 1) ? 10 : (wvu == 2) ? 14 : 18;
        for (int j = j0; j < j1; ++j) {
            const int cs = cbase + j;
            GLOAD_LDS16(aBase + (size_t)cs * 512 + lane8, &As[cs & 31][0]);
        }
        GLOAD_LDS16(bPanel + (0 * 4 + wvu) * 512 + lane8, &Bs[0][wvu][0]);
        GLOAD_LDS16(bPanel + (1 * 4 + wvu) * 512 + lane8, &Bs[1][wvu][0]);
    }
    WBAR0;   // everything for steps 0,1 resident

    int ab  = 127 - nt16 - 4 * wvu;
    int csw = 131 - nt16 - wvu;
    const ushort* aSt = aBase + (size_t)(131 - nt16 - wvu) * 512 + lane8;
    const ushort* bSt = bPanel + (2 * 4 + wvu) * 512 + lane8;

    // rotation pre-seed: "previous a0,a1" = frags (ab-2),(ab-3)
    shortx8 a0, a1, a2, a3;
    a0 = *(const shortx8*)(&As[(ab - 2) & 31][lane8]);
    a1 = *(const shortx8*)(&As[(ab - 3) & 31][lane8]);

    // ---- main loop: tc = 0..59 (15 x 4 steps), staging S(tc+2)
    for (int u = 0; u < 15; ++u) {
        STEP(0, 0, 1); WBAR;
        STEP(1, 1, 1); WBAR;
        STEP(2, 2, 1); WBAR;
        STEP(3, 3, 1); WBAR;
        ab += 8; csw += 8; aSt += 4 * 1024; bSt += 4 * 2048;
    }
    // ---- tail: tc = 60..63
    STEP(0, 0, 1); WBAR;    // tc=60: stages S(62)
    STEP(1, 1, 1); WBAR;    // tc=61: stages S(63)
    STEP(2, 2, 0); WBAR0;   // tc=62: drain S(63)
    STEP(3, 3, 0);          // tc=63: final compute

    // epilogue: D row=(lane>>4)*4+r (n-local), col=lane&15 (d-local)
    const int q    = lane >> 4;
    const int dcol = lane & 15;
    const int nB   = nt * 256 + wvu * 64;
#pragma unroll
    for (int s = 0; s < 4; ++s) {
        int nsb = nB + s * 16 + q * 4;
#pragma unroll
        for (int r = 0; r < 4; ++r) {
            int n = nsb + r;
            if (n < SEQ) {
                float* ob = out + ((size_t)(bb * MAXPOS + 1 + n) * NH + h) * HD + dcol;
#pragma unroll
                for (int dt = 0; dt < 4; ++dt) ob[dt * 16] = acc[s][dt][r];
            }
        }
    }
}

extern "C" void kernel_launch(void* const* d_in, const int* in_sizes, int n_in,
                              void* d_out, int out_size, void* d_ws, size_t ws_size,
                              hipStream_t stream) {
    const float* v   = (const float*)d_in[0];  // (8, 2048, 12, 64)
    const float* off = (const float*)d_in[1];  // (1, 12)
    const float* w   = (const float*)d_in[2];  // (1, 12, 2046)
    float* out = (float*)d_out;

    ushort* atile = (ushort*)d_ws;
    ushort* vbf   = (ushort*)((char*)d_ws + ATILE_BYTES);

    prep_all<<<NB_V2 + NB_ZPB + NB_A + 48, 256, 0, stream>>>(v, w, off, atile, vbf, out);
    gemm_pbv<<<768, 256, 0, stream>>>(atile, vbf, out);
}